// Round 9
// baseline (188.228 us; speedup 1.0000x reference)
//
#include <hip/hip_runtime.h>
#include <math.h>

#define VV 8192
#define DD 768
#define NDMAX 256

typedef __attribute__((ext_vector_type(8))) short bf16x8;
typedef __attribute__((ext_vector_type(4))) float f32x4;

// RNE float -> bf16 bits
__device__ inline ushort f2bf(float f) {
    uint u = __float_as_uint(f);
    uint r = (u + 0x7fffu + ((u >> 16) & 1u)) >> 16;
    return (ushort)r;
}
__device__ inline float bf2f(ushort h) { return __uint_as_float(((uint)h) << 16); }

__device__ inline void gload16(const ushort* g, ushort* l) {
    __builtin_amdgcn_global_load_lds(
        (const __attribute__((address_space(1))) void*)g,
        (__attribute__((address_space(3))) void*)l, 16, 0, 0);
}

// ---------------------------------------------------------------------------
// k_normpack: L2-normalize rows (fp64 norm accum) -> xh/xl (bf16 hi/lo split)
// + norms[r]. Also zeroes g and rc.
// ---------------------------------------------------------------------------
__global__ __launch_bounds__(256) void k_normpack(const float* __restrict__ t,
                                                  float* __restrict__ norms,
                                                  ushort* __restrict__ xh,
                                                  ushort* __restrict__ xl,
                                                  double* __restrict__ g,
                                                  float* __restrict__ rc) {
    int r = blockIdx.x;
    const float* tr = t + (size_t)r * DD;
    int tid = threadIdx.x;
    float v0 = tr[tid], v1 = tr[tid + 256], v2 = tr[tid + 512];
    double s = (double)v0 * v0 + (double)v1 * v1 + (double)v2 * v2;
#pragma unroll
    for (int o = 32; o > 0; o >>= 1) s += __shfl_down(s, o, 64);
    __shared__ double wsum[4];
    int lane = tid & 63, w = tid >> 6;
    if (lane == 0) wsum[w] = s;
    __syncthreads();
    double tot = wsum[0] + wsum[1] + wsum[2] + wsum[3];
    float norm = fmaxf((float)sqrt(tot), 1e-12f);
    if (tid == 0) {
        norms[r] = norm;
        rc[r] = 0.f;
        if (r < DD) g[r] = 0.0;
    }
    size_t base = (size_t)r * DD;
#pragma unroll
    for (int q = 0; q < 3; ++q) {
        int k = tid + q * 256;
        float v = (q == 0 ? v0 : (q == 1 ? v1 : v2)) / norm;
        ushort h = f2bf(v);
        xh[base + k] = h;
        xl[base + k] = f2bf(v - bf2f(h));
    }
}

// ---------------------------------------------------------------------------
// k_colsum: g[k] = sum over rows of fp32(t[r][k]/norm[r]), fp64 accum.
// ---------------------------------------------------------------------------
__global__ __launch_bounds__(256) void k_colsum(const float* __restrict__ t,
                                                const float* __restrict__ norms,
                                                double* __restrict__ g) {
    int k = threadIdx.x;
    int r0 = blockIdx.x * 32;
    double s0 = 0.0, s1 = 0.0, s2 = 0.0;
    for (int r = r0; r < r0 + 32; ++r) {
        const float* tr = t + (size_t)r * DD;
        float nrm = norms[r];
        s0 += (double)(tr[k] / nrm);
        s1 += (double)(tr[k + 256] / nrm);
        s2 += (double)(tr[k + 512] / nrm);
    }
    atomicAdd(&g[k], s0);
    atomicAdd(&g[k + 256], s1);
    atomicAdd(&g[k + 512], s2);
}

// ---------------------------------------------------------------------------
// k_mean: mnum[r] = x_r.g - x_r.x_r (fp64); dd[r] = x_r.x_r.
// Exact mean path -- numerically deadly, do not approximate.
// ---------------------------------------------------------------------------
__global__ __launch_bounds__(256) void k_mean(const float* __restrict__ t,
                                              const float* __restrict__ norms,
                                              const double* __restrict__ g,
                                              double* __restrict__ mnum,
                                              double* __restrict__ dd) {
    int r = blockIdx.x * 4 + (threadIdx.x >> 6);
    int lane = threadIdx.x & 63;
    const float* tr = t + (size_t)r * DD;
    float nrm = norms[r];
    double xg = 0.0, xx = 0.0;
#pragma unroll
    for (int k = lane; k < DD; k += 64) {
        float xf = tr[k] / nrm;
        double xv = (double)xf;
        xg += xv * g[k];
        xx += xv * xv;
    }
#pragma unroll
    for (int o = 32; o > 0; o >>= 1) {
        xg += __shfl_down(xg, o, 64);
        xx += __shfl_down(xx, o, 64);
    }
    if (lane == 0) {
        mnum[r] = xg - xx;
        dd[r] = xx;
    }
}

// ---------------------------------------------------------------------------
// k_select: deterministic row-sorted compaction of danger rows
// (|mean_neg+eps| < 1e-5).
// ---------------------------------------------------------------------------
__global__ __launch_bounds__(256) void k_select(const double* __restrict__ mnum,
                                                int* __restrict__ dlist) {
    __shared__ int cnts[256];
    int tid = threadIdx.x;
    dlist[tid] = -1;
    int r0 = tid * 32;
    int c = 0;
    for (int i = 0; i < 32; ++i) {
        double md = fabs(mnum[r0 + i] / 8191.0 + 1e-6);
        if (md < 1e-5) ++c;
    }
    cnts[tid] = c;
    __syncthreads();
    int pre = 0;
    for (int i = 0; i < tid; ++i) pre += cnts[i];
    for (int i = 0; i < 32; ++i) {
        int r = r0 + i;
        double md = fabs(mnum[r] / 8191.0 + 1e-6);
        if (md < 1e-5) {
            if (pre < NDMAX) dlist[pre] = r;
            ++pre;
        }
    }
}

// ---------------------------------------------------------------------------
// k_cube: m97-structure bf16 MFMA pass. 128x128 tile, 256 threads (4 waves,
// 2Mx2N, per-wave 64x64 = 4x4 frags of 16x16x32), BK=32 double-buffered
// (LDS 32 KiB -> ~3 blocks/CU, 12 waves/CU: inter-block wave overlap does
// the pipelining -- m114/m97 mechanism). NO inline asm, NO sched_barrier:
// one __syncthreads() per K-step, compiler-scheduled waitcnts.
// LDS [128][32] bf16 per buffer; read-slot swizzle li4^((l15>>1)&3)
// (measured conflict-free); staged via global_load_lds w=16 with
// pre-swizzled per-lane source, linear dest.
// Grid 2464, all blocks uniform (24 K-steps):
//  - bids 0..383: strip-partial (seg 0..2 x rowpanel 0..1 x colpanel 0..63):
//    danger rows (gathered) x 128 cols -> store partial S into Sb (no cube).
//  - bids 384..2463: big triangle tiles (hh only), 2080 = 8*260 bijective
//    XCD swizzle; cube + row/col sums via symmetry.
// ---------------------------------------------------------------------------
__global__ __launch_bounds__(256, 3) void k_cube(const ushort* __restrict__ xh,
                                                 const ushort* __restrict__ xl,
                                                 const int* __restrict__ dlist,
                                                 float* __restrict__ Sb,
                                                 float* __restrict__ rc) {
    __shared__ ushort As[2][4096];  // [buf][128 rows][32 k] bf16 = 8 KB each
    __shared__ ushort Bs[2][4096];

    const int bid = blockIdx.x;
    const int tid = threadIdx.x;
    const int lane = tid & 63;
    const int wid = tid >> 6;
    const int l15 = lane & 15, li4 = lane >> 4;
    const int wm = wid >> 1, wn = wid & 1;

    const bool strip = (bid < 384);
    int bi = 0, bj = 0, seg = 0, rp = 0, cp = 0;
    if (strip) {
        seg = bid >> 7;
        int rem = bid & 127;
        rp = rem >> 6;
        cp = rem & 63;
    } else {
        int idx = bid - 384;
        int wg = (idx & 7) * 260 + (idx >> 3);  // XCD-bijective (2080 = 8*260)
        int rem = wg;
        while (rem >= 64 - bi) { rem -= 64 - bi; ++bi; }
        bj = bi + rem;
    }
    const ushort* XA = strip ? ((seg == 1) ? xl : xh) : xh;
    const ushort* XB = strip ? ((seg == 2) ? xl : xh) : xh;

    // staging descriptors: 2 gloads/thread per matrix per K-step
    int asrc[2], bsrc[2], ldst[2];
#pragma unroll
    for (int j = 0; j < 2; ++j) {
        int li = tid + j * 256;                    // 0..511
        int row = li >> 2;                         // 0..127
        int sl = ((li & 3) ^ ((li >> 3) & 3)) * 8; // pre-swizzled source slot
        int ar = strip ? dlist[rp * 128 + row] : (bi * 128 + row);
        if (ar < 0) ar = 0;
        int br = strip ? (cp * 128 + row) : (bj * 128 + row);
        asrc[j] = ar * DD + sl;
        bsrc[j] = br * DD + sl;
        ldst[j] = li * 8;                          // linear LDS dest (ushorts)
    }

    const int swz = (li4 ^ ((l15 >> 1) & 3)) << 3;
    const int aoff = (wm * 64 + l15) * 32 + swz;
    const int boff = (wn * 64 + l15) * 32 + swz;

    f32x4 acc[4][4];
#pragma unroll
    for (int f = 0; f < 4; ++f)
#pragma unroll
        for (int n = 0; n < 4; ++n) acc[f][n] = (f32x4){0.f, 0.f, 0.f, 0.f};

    // prologue: stage K-step 0 into buf 0
#pragma unroll
    for (int j = 0; j < 2; ++j) {
        gload16(XA + asrc[j], As[0] + ldst[j]);
        gload16(XB + bsrc[j], Bs[0] + ldst[j]);
    }
    __syncthreads();

    for (int t = 0; t < 24; ++t) {
        const int cur = t & 1;
        if (t < 23) {
            const int k1 = (t + 1) * 32;
#pragma unroll
            for (int j = 0; j < 2; ++j) {
                gload16(XA + asrc[j] + k1, As[cur ^ 1] + ldst[j]);
                gload16(XB + bsrc[j] + k1, Bs[cur ^ 1] + ldst[j]);
            }
        }
        bf16x8 av[4], bv[4];
#pragma unroll
        for (int f = 0; f < 4; ++f) {
            av[f] = *(const bf16x8*)(As[cur] + aoff + f * 512);
            bv[f] = *(const bf16x8*)(Bs[cur] + boff + f * 512);
        }
#pragma unroll
        for (int f = 0; f < 4; ++f)
#pragma unroll
            for (int n = 0; n < 4; ++n)
                acc[f][n] = __builtin_amdgcn_mfma_f32_16x16x32_bf16(
                    av[f], bv[n], acc[f][n], 0, 0, 0);
        __syncthreads();  // stages landed (vmcnt drain) + all reads of cur done
    }

    if (strip) {
        // store partial S (f32) by danger slot; finish pass cubes later
#pragma unroll
        for (int f = 0; f < 4; ++f)
#pragma unroll
            for (int n = 0; n < 4; ++n)
#pragma unroll
                for (int r = 0; r < 4; ++r) {
                    int slot = seg * 256 + rp * 128 + wm * 64 + f * 16 + li4 * 4 + r;
                    int col = cp * 128 + wn * 64 + n * 16 + l15;
                    Sb[((size_t)slot << 13) + col] = acc[f][n][r];
                }
        return;
    }

    // big-tile epilogue: cube, skip diag, row + col (symmetry) sums
    const bool dblk = (bi == bj);
    const int R0 = bi * 128, C0 = bj * 128;
    float rsum[4][4], csum[4];
#pragma unroll
    for (int n = 0; n < 4; ++n) csum[n] = 0.f;
#pragma unroll
    for (int f = 0; f < 4; ++f)
#pragma unroll
        for (int r = 0; r < 4; ++r) rsum[f][r] = 0.f;
#pragma unroll
    for (int f = 0; f < 4; ++f)
#pragma unroll
        for (int n = 0; n < 4; ++n)
#pragma unroll
            for (int r = 0; r < 4; ++r) {
                float s = acc[f][n][r];
                float c = s * s * s;
                int ri = wm * 64 + f * 16 + li4 * 4 + r;
                int cj = wn * 64 + n * 16 + l15;
                if (dblk && ri == cj) c = 0.f;
                rsum[f][r] += c;
                csum[n] += c;
            }
    // row side: reduce across the 16 col-lanes (l15)
#pragma unroll
    for (int o = 1; o < 16; o <<= 1)
#pragma unroll
        for (int f = 0; f < 4; ++f)
#pragma unroll
            for (int r = 0; r < 4; ++r)
                rsum[f][r] += __shfl_xor(rsum[f][r], o, 64);
    if (l15 == 0) {
#pragma unroll
        for (int f = 0; f < 4; ++f)
#pragma unroll
            for (int r = 0; r < 4; ++r)
                atomicAdd(&rc[R0 + wm * 64 + f * 16 + li4 * 4 + r], rsum[f][r]);
    }
    // col side (rows bj*.. of S by symmetry; off-diag blocks only)
    if (!dblk) {
#pragma unroll
        for (int o = 16; o < 64; o <<= 1)
#pragma unroll
            for (int n = 0; n < 4; ++n) csum[n] += __shfl_xor(csum[n], o, 64);
        if (li4 == 0) {
#pragma unroll
            for (int n = 0; n < 4; ++n)
                atomicAdd(&rc[C0 + wn * 64 + n * 16 + l15], csum[n]);
        }
    }
}

// ---------------------------------------------------------------------------
// k_cubefin: per danger slot, correction = sum_c [(s0+s1+s2)^3 - s0^3]
// (skip c == drow; s0 bitwise-equals the big pass's hh value, so the
// subtraction exactly removes the hh-cube already in rc).
// ---------------------------------------------------------------------------
__global__ __launch_bounds__(256) void k_cubefin(const float* __restrict__ Sb,
                                                 const int* __restrict__ dlist,
                                                 float* __restrict__ rc) {
    const int slot = blockIdx.x;
    const int drow = dlist[slot];
    if (drow < 0) return;
    const int tid = threadIdx.x;
    const float* s0p = Sb + ((size_t)slot << 13);
    const float* s1p = Sb + ((size_t)(256 + slot) << 13);
    const float* s2p = Sb + ((size_t)(512 + slot) << 13);
    float sum = 0.f;
    for (int c = tid; c < VV; c += 256) {
        float s0 = s0p[c];
        float sf = s0 + s1p[c] + s2p[c];
        float d = sf * sf * sf - s0 * s0 * s0;
        if (c == drow) d = 0.f;
        sum += d;
    }
    __shared__ float red[256];
    red[tid] = sum;
    __syncthreads();
    for (int o = 128; o > 0; o >>= 1) {
        if (tid < o) red[tid] += red[tid + o];
        __syncthreads();
    }
    if (tid == 0) atomicAdd(&rc[drow], red[0]);
}

// ---------------------------------------------------------------------------
// k_final: out = collapse + 0.2 * sum_i rc_i / (mnum_i/8191 + 1e-6)
// ---------------------------------------------------------------------------
__global__ __launch_bounds__(256) void k_final(const float* __restrict__ rc,
                                               const double* __restrict__ mnum,
                                               const double* __restrict__ dd,
                                               float* __restrict__ out) {
    int tid = threadIdx.x;
    double acc = 0.0, col = 0.0;
    for (int r = tid; r < VV; r += 256) {
        double m = mnum[r] / 8191.0 + 1e-6;
        acc += (double)rc[r] / m;
        double dm = dd[r] - 1.0;
        col += dm * dm;
    }
    __shared__ double sa[256], sc[256];
    sa[tid] = acc;
    sc[tid] = col;
    __syncthreads();
    for (int o = 128; o > 0; o >>= 1) {
        if (tid < o) {
            sa[tid] += sa[tid + o];
            sc[tid] += sc[tid + o];
        }
        __syncthreads();
    }
    if (tid == 0) out[0] = (float)(sc[0] + 0.2 * sa[0]);
}

// ---------------------------------------------------------------------------
extern "C" void kernel_launch(void* const* d_in, const int* in_sizes, int n_in,
                              void* d_out, int out_size, void* d_ws, size_t ws_size,
                              hipStream_t stream) {
    const float* t = (const float*)d_in[0];
    float* out = (float*)d_out;

    char* ws = (char*)d_ws;
    float* Sb = (float*)ws;  // 3*256*8192*4B = 24 MB
    size_t off = (size_t)VV * DD * sizeof(float);  // keep 25.2 MB region
    ushort* xh = (ushort*)(ws + off); off += (size_t)VV * DD * sizeof(ushort);
    ushort* xl = (ushort*)(ws + off); off += (size_t)VV * DD * sizeof(ushort);
    double* g = (double*)(ws + off);  off += DD * sizeof(double);
    double* mnum = (double*)(ws + off); off += VV * sizeof(double);
    double* dd = (double*)(ws + off);  off += VV * sizeof(double);
    float* rc = (float*)(ws + off);    off += VV * sizeof(float);
    int* dlist = (int*)(ws + off);     off += NDMAX * sizeof(int);
    float* norms = (float*)(ws + off); off += VV * sizeof(float);

    k_normpack<<<VV, 256, 0, stream>>>(t, norms, xh, xl, g, rc);
    k_colsum<<<256, 256, 0, stream>>>(t, norms, g);
    k_mean<<<VV / 4, 256, 0, stream>>>(t, norms, g, mnum, dd);
    k_select<<<1, 256, 0, stream>>>(mnum, dlist);
    k_cube<<<2464, 256, 0, stream>>>(xh, xl, dlist, Sb, rc);
    k_cubefin<<<NDMAX, 256, 0, stream>>>(Sb, dlist, rc);
    k_final<<<1, 256, 0, stream>>>(rc, mnum, dd, out);
}

// Round 10
// 160.213 us; speedup vs baseline: 1.1749x; 1.1749x over previous
//
#include <hip/hip_runtime.h>
#include <math.h>

#define VV 8192
#define DD 768
#define NDMAX 256

typedef __attribute__((ext_vector_type(8))) short bf16x8;
typedef __attribute__((ext_vector_type(4))) float f32x4;

// RNE float -> bf16 bits
__device__ inline ushort f2bf(float f) {
    uint u = __float_as_uint(f);
    uint r = (u + 0x7fffu + ((u >> 16) & 1u)) >> 16;
    return (ushort)r;
}
__device__ inline float bf2f(ushort h) { return __uint_as_float(((uint)h) << 16); }

__device__ inline void gload16(const ushort* g, ushort* l) {
    __builtin_amdgcn_global_load_lds(
        (const __attribute__((address_space(1))) void*)g,
        (__attribute__((address_space(3))) void*)l, 16, 0, 0);
}

// ---------------------------------------------------------------------------
// k_normpack: L2-normalize rows (fp64 norm accum) -> xh/xl (bf16 hi/lo split)
// + norms[r]. Also zeroes g, rc, dlist, dcount.
// ---------------------------------------------------------------------------
__global__ __launch_bounds__(256) void k_normpack(const float* __restrict__ t,
                                                  float* __restrict__ norms,
                                                  ushort* __restrict__ xh,
                                                  ushort* __restrict__ xl,
                                                  double* __restrict__ g,
                                                  float* __restrict__ rc,
                                                  int* __restrict__ dlist,
                                                  int* __restrict__ dcount) {
    int r = blockIdx.x;
    const float* tr = t + (size_t)r * DD;
    int tid = threadIdx.x;
    float v0 = tr[tid], v1 = tr[tid + 256], v2 = tr[tid + 512];
    double s = (double)v0 * v0 + (double)v1 * v1 + (double)v2 * v2;
#pragma unroll
    for (int o = 32; o > 0; o >>= 1) s += __shfl_down(s, o, 64);
    __shared__ double wsum[4];
    int lane = tid & 63, w = tid >> 6;
    if (lane == 0) wsum[w] = s;
    __syncthreads();
    double tot = wsum[0] + wsum[1] + wsum[2] + wsum[3];
    float norm = fmaxf((float)sqrt(tot), 1e-12f);
    if (tid == 0) {
        norms[r] = norm;
        rc[r] = 0.f;
        if (r < DD) g[r] = 0.0;
    }
    if (r == 0) {
        dlist[tid] = -1;
        if (tid == 0) *dcount = 0;
    }
    size_t base = (size_t)r * DD;
#pragma unroll
    for (int q = 0; q < 3; ++q) {
        int k = tid + q * 256;
        float v = (q == 0 ? v0 : (q == 1 ? v1 : v2)) / norm;
        ushort h = f2bf(v);
        xh[base + k] = h;
        xl[base + k] = f2bf(v - bf2f(h));
    }
}

// ---------------------------------------------------------------------------
// k_colsum: g[k] = sum over rows of fp32(t[r][k]/norm[r]), fp64 accum.
// ---------------------------------------------------------------------------
__global__ __launch_bounds__(256) void k_colsum(const float* __restrict__ t,
                                                const float* __restrict__ norms,
                                                double* __restrict__ g) {
    int k = threadIdx.x;
    int r0 = blockIdx.x * 32;
    double s0 = 0.0, s1 = 0.0, s2 = 0.0;
    for (int r = r0; r < r0 + 32; ++r) {
        const float* tr = t + (size_t)r * DD;
        float nrm = norms[r];
        s0 += (double)(tr[k] / nrm);
        s1 += (double)(tr[k + 256] / nrm);
        s2 += (double)(tr[k + 512] / nrm);
    }
    atomicAdd(&g[k], s0);
    atomicAdd(&g[k + 256], s1);
    atomicAdd(&g[k + 512], s2);
}

// ---------------------------------------------------------------------------
// k_mean: mnum[r] = x_r.g - x_r.x_r (fp64); dd[r] = x_r.x_r. Exact mean
// path -- numerically deadly, do not approximate. Danger-row selection
// fused here (atomic compaction; slot order irrelevant: per-row correction
// value is independent of slot).
// ---------------------------------------------------------------------------
__global__ __launch_bounds__(256) void k_mean(const float* __restrict__ t,
                                              const float* __restrict__ norms,
                                              const double* __restrict__ g,
                                              double* __restrict__ mnum,
                                              double* __restrict__ dd,
                                              int* __restrict__ dlist,
                                              int* __restrict__ dcount) {
    int r = blockIdx.x * 4 + (threadIdx.x >> 6);
    int lane = threadIdx.x & 63;
    const float* tr = t + (size_t)r * DD;
    float nrm = norms[r];
    double xg = 0.0, xx = 0.0;
#pragma unroll
    for (int k = lane; k < DD; k += 64) {
        float xf = tr[k] / nrm;
        double xv = (double)xf;
        xg += xv * g[k];
        xx += xv * xv;
    }
#pragma unroll
    for (int o = 32; o > 0; o >>= 1) {
        xg += __shfl_down(xg, o, 64);
        xx += __shfl_down(xx, o, 64);
    }
    if (lane == 0) {
        double m = xg - xx;
        mnum[r] = m;
        dd[r] = xx;
        if (fabs(m / 8191.0 + 1e-6) < 1e-5) {
            int pos = atomicAdd(dcount, 1);
            if (pos < NDMAX) dlist[pos] = r;
        }
    }
}

// ---------------------------------------------------------------------------
// k_cube: 128x128-tile bf16 MFMA pass, BK=32, TRIPLE-buffered staging with
// prefetch distance 2 and counted vmcnt(4) (never 0 mid-loop) + raw
// s_barrier -- the waited loads were issued two full K-steps (~2000 cy)
// earlier, so the per-step drain is ~free. 256 threads (4 waves 2Mx2N,
// per-wave 64x64), LDS 48 KiB -> 3 blocks/CU (12 waves/CU). No
// sched_barrier, no setprio: compiler keeps scheduling freedom.
// LDS [128][32] bf16 per buffer; read-slot swizzle li4^((l15>>1)&3)
// (measured conflict-free); staged via global_load_lds w=16 with
// pre-swizzled per-lane source, linear dest.
// Grid 2464, uniform blocks (24 K-steps):
//  - bids 0..383: strip-partial (seg x rowpanel x colpanel): danger rows
//    (gathered) x 128 cols -> store partial S into Sb (no cube).
//  - bids 384..2463: big triangle tiles (hh only), 2080 = 8*260 bijective
//    XCD swizzle; cube + row/col sums via symmetry.
// ---------------------------------------------------------------------------
__global__ __launch_bounds__(256, 3) void k_cube(const ushort* __restrict__ xh,
                                                 const ushort* __restrict__ xl,
                                                 const int* __restrict__ dlist,
                                                 float* __restrict__ Sb,
                                                 float* __restrict__ rc) {
    __shared__ ushort As0[4096], As1[4096], As2[4096];
    __shared__ ushort Bs0[4096], Bs1[4096], Bs2[4096];

    const int bid = blockIdx.x;
    const int tid = threadIdx.x;
    const int lane = tid & 63;
    const int wid = tid >> 6;
    const int l15 = lane & 15, li4 = lane >> 4;
    const int wm = wid >> 1, wn = wid & 1;

    const bool strip = (bid < 384);
    int bi = 0, bj = 0, seg = 0, rp = 0, cp = 0;
    if (strip) {
        seg = bid >> 7;
        int rem = bid & 127;
        rp = rem >> 6;
        cp = rem & 63;
    } else {
        int idx = bid - 384;
        int wg = (idx & 7) * 260 + (idx >> 3);  // XCD-bijective (2080 = 8*260)
        int rem = wg;
        while (rem >= 64 - bi) { rem -= 64 - bi; ++bi; }
        bj = bi + rem;
    }
    const ushort* XA = strip ? ((seg == 1) ? xl : xh) : xh;
    const ushort* XB = strip ? ((seg == 2) ? xl : xh) : xh;

    // staging descriptors: 2 gloads/thread per matrix per K-step
    int asrc[2], bsrc[2], ldst[2];
#pragma unroll
    for (int j = 0; j < 2; ++j) {
        int li = tid + j * 256;                    // 0..511
        int row = li >> 2;                         // 0..127
        int sl = ((li & 3) ^ ((li >> 3) & 3)) * 8; // pre-swizzled source slot
        int ar = strip ? dlist[rp * 128 + row] : (bi * 128 + row);
        if (ar < 0) ar = 0;
        int br = strip ? (cp * 128 + row) : (bj * 128 + row);
        asrc[j] = ar * DD + sl;
        bsrc[j] = br * DD + sl;
        ldst[j] = li * 8;                          // linear LDS dest (ushorts)
    }

    const int swz = (li4 ^ ((l15 >> 1) & 3)) << 3;
    const int aoff = (wm * 64 + l15) * 32 + swz;
    const int boff = (wn * 64 + l15) * 32 + swz;

    f32x4 acc[4][4];
#pragma unroll
    for (int f = 0; f < 4; ++f)
#pragma unroll
        for (int n = 0; n < 4; ++n) acc[f][n] = (f32x4){0.f, 0.f, 0.f, 0.f};

#define STG(AW, BW, KT)                                  \
    do {                                                 \
        const int kq_ = (KT) * 32;                       \
        gload16(XA + asrc[0] + kq_, (AW) + ldst[0]);     \
        gload16(XB + bsrc[0] + kq_, (BW) + ldst[0]);     \
        gload16(XA + asrc[1] + kq_, (AW) + ldst[1]);     \
        gload16(XB + bsrc[1] + kq_, (BW) + ldst[1]);     \
    } while (0)

#define COMPUTE(AR, BR)                                                     \
    do {                                                                    \
        bf16x8 av[4], bv[4];                                                \
        _Pragma("unroll") for (int f = 0; f < 4; ++f) {                     \
            av[f] = *(const bf16x8*)((AR) + aoff + f * 512);                \
            bv[f] = *(const bf16x8*)((BR) + boff + f * 512);                \
        }                                                                   \
        _Pragma("unroll") for (int f = 0; f < 4; ++f)                       \
            _Pragma("unroll") for (int n = 0; n < 4; ++n)                   \
                acc[f][n] = __builtin_amdgcn_mfma_f32_16x16x32_bf16(        \
                    av[f], bv[n], acc[f][n], 0, 0, 0);                      \
    } while (0)

#define VMW4() asm volatile("s_waitcnt vmcnt(4)" ::: "memory")
#define VMW0() asm volatile("s_waitcnt vmcnt(0)" ::: "memory")
#define RBAR() asm volatile("s_barrier" ::: "memory")

    // prologue: stage steps 0 and 1
    STG(As0, Bs0, 0);
    STG(As1, Bs1, 1);
    VMW4(); RBAR();  // step-0 loads landed

    // main loop: steps 0..20 (7 triples), each stages t+2, waits vmcnt(4)
    for (int tb = 0; tb < 21; tb += 3) {
        STG(As2, Bs2, tb + 2);
        COMPUTE(As0, Bs0);
        VMW4(); RBAR();
        STG(As0, Bs0, tb + 3);
        COMPUTE(As1, Bs1);
        VMW4(); RBAR();
        STG(As1, Bs1, tb + 4);
        COMPUTE(As2, Bs2);
        VMW4(); RBAR();
    }
    // t=21: stage 23 -> buf2; t=22, t=23 drain
    STG(As2, Bs2, 23);
    COMPUTE(As0, Bs0);
    VMW4(); RBAR();
    COMPUTE(As1, Bs1);
    VMW0(); RBAR();
    COMPUTE(As2, Bs2);
#undef STG
#undef COMPUTE
#undef VMW4
#undef VMW0
#undef RBAR

    if (strip) {
        // store partial S (f32) by danger slot; finish pass cubes later
#pragma unroll
        for (int f = 0; f < 4; ++f)
#pragma unroll
            for (int n = 0; n < 4; ++n)
#pragma unroll
                for (int r = 0; r < 4; ++r) {
                    int slot = seg * 256 + rp * 128 + wm * 64 + f * 16 + li4 * 4 + r;
                    int col = cp * 128 + wn * 64 + n * 16 + l15;
                    Sb[((size_t)slot << 13) + col] = acc[f][n][r];
                }
        return;
    }

    // big-tile epilogue: cube, skip diag, row + col (symmetry) sums
    const bool dblk = (bi == bj);
    const int R0 = bi * 128, C0 = bj * 128;
    float rsum[4][4], csum[4];
#pragma unroll
    for (int n = 0; n < 4; ++n) csum[n] = 0.f;
#pragma unroll
    for (int f = 0; f < 4; ++f)
#pragma unroll
        for (int r = 0; r < 4; ++r) rsum[f][r] = 0.f;
#pragma unroll
    for (int f = 0; f < 4; ++f)
#pragma unroll
        for (int n = 0; n < 4; ++n)
#pragma unroll
            for (int r = 0; r < 4; ++r) {
                float s = acc[f][n][r];
                float c = s * s * s;
                int ri = wm * 64 + f * 16 + li4 * 4 + r;
                int cj = wn * 64 + n * 16 + l15;
                if (dblk && ri == cj) c = 0.f;
                rsum[f][r] += c;
                csum[n] += c;
            }
    // row side: reduce across the 16 col-lanes (l15)
#pragma unroll
    for (int o = 1; o < 16; o <<= 1)
#pragma unroll
        for (int f = 0; f < 4; ++f)
#pragma unroll
            for (int r = 0; r < 4; ++r)
                rsum[f][r] += __shfl_xor(rsum[f][r], o, 64);
    if (l15 == 0) {
#pragma unroll
        for (int f = 0; f < 4; ++f)
#pragma unroll
            for (int r = 0; r < 4; ++r)
                atomicAdd(&rc[R0 + wm * 64 + f * 16 + li4 * 4 + r], rsum[f][r]);
    }
    // col side (rows bj*.. of S by symmetry; off-diag blocks only)
    if (!dblk) {
#pragma unroll
        for (int o = 16; o < 64; o <<= 1)
#pragma unroll
            for (int n = 0; n < 4; ++n) csum[n] += __shfl_xor(csum[n], o, 64);
        if (li4 == 0) {
#pragma unroll
            for (int n = 0; n < 4; ++n)
                atomicAdd(&rc[C0 + wn * 64 + n * 16 + l15], csum[n]);
        }
    }
}

// ---------------------------------------------------------------------------
// k_cubefin: per danger slot, correction = sum_c [(s0+s1+s2)^3 - s0^3]
// (skip c == drow; s0 bitwise-equals the big pass's hh value, so the
// subtraction exactly removes the hh-cube already in rc).
// ---------------------------------------------------------------------------
__global__ __launch_bounds__(256) void k_cubefin(const float* __restrict__ Sb,
                                                 const int* __restrict__ dlist,
                                                 float* __restrict__ rc) {
    const int slot = blockIdx.x;
    const int drow = dlist[slot];
    if (drow < 0) return;
    const int tid = threadIdx.x;
    const float* s0p = Sb + ((size_t)slot << 13);
    const float* s1p = Sb + ((size_t)(256 + slot) << 13);
    const float* s2p = Sb + ((size_t)(512 + slot) << 13);
    float sum = 0.f;
    for (int c = tid; c < VV; c += 256) {
        float s0 = s0p[c];
        float sf = s0 + s1p[c] + s2p[c];
        float d = sf * sf * sf - s0 * s0 * s0;
        if (c == drow) d = 0.f;
        sum += d;
    }
    __shared__ float red[256];
    red[tid] = sum;
    __syncthreads();
    for (int o = 128; o > 0; o >>= 1) {
        if (tid < o) red[tid] += red[tid + o];
        __syncthreads();
    }
    if (tid == 0) atomicAdd(&rc[drow], red[0]);
}

// ---------------------------------------------------------------------------
// k_final: out = collapse + 0.2 * sum_i rc_i / (mnum_i/8191 + 1e-6)
// ---------------------------------------------------------------------------
__global__ __launch_bounds__(256) void k_final(const float* __restrict__ rc,
                                               const double* __restrict__ mnum,
                                               const double* __restrict__ dd,
                                               float* __restrict__ out) {
    int tid = threadIdx.x;
    double acc = 0.0, col = 0.0;
    for (int r = tid; r < VV; r += 256) {
        double m = mnum[r] / 8191.0 + 1e-6;
        acc += (double)rc[r] / m;
        double dm = dd[r] - 1.0;
        col += dm * dm;
    }
    __shared__ double sa[256], sc[256];
    sa[tid] = acc;
    sc[tid] = col;
    __syncthreads();
    for (int o = 128; o > 0; o >>= 1) {
        if (tid < o) {
            sa[tid] += sa[tid + o];
            sc[tid] += sc[tid + o];
        }
        __syncthreads();
    }
    if (tid == 0) out[0] = (float)(sc[0] + 0.2 * sa[0]);
}

// ---------------------------------------------------------------------------
extern "C" void kernel_launch(void* const* d_in, const int* in_sizes, int n_in,
                              void* d_out, int out_size, void* d_ws, size_t ws_size,
                              hipStream_t stream) {
    const float* t = (const float*)d_in[0];
    float* out = (float*)d_out;

    char* ws = (char*)d_ws;
    float* Sb = (float*)ws;  // 3*256*8192*4B = 24 MB
    size_t off = (size_t)VV * DD * sizeof(float);  // keep 25.2 MB region
    ushort* xh = (ushort*)(ws + off); off += (size_t)VV * DD * sizeof(ushort);
    ushort* xl = (ushort*)(ws + off); off += (size_t)VV * DD * sizeof(ushort);
    double* g = (double*)(ws + off);  off += DD * sizeof(double);
    double* mnum = (double*)(ws + off); off += VV * sizeof(double);
    double* dd = (double*)(ws + off);  off += VV * sizeof(double);
    float* rc = (float*)(ws + off);    off += VV * sizeof(float);
    int* dlist = (int*)(ws + off);     off += NDMAX * sizeof(int);
    int* dcount = (int*)(ws + off);    off += sizeof(int) + 60;  // pad
    float* norms = (float*)(ws + off); off += VV * sizeof(float);

    k_normpack<<<VV, 256, 0, stream>>>(t, norms, xh, xl, g, rc, dlist, dcount);
    k_colsum<<<256, 256, 0, stream>>>(t, norms, g);
    k_mean<<<VV / 4, 256, 0, stream>>>(t, norms, g, mnum, dd, dlist, dcount);
    k_cube<<<2464, 256, 0, stream>>>(xh, xl, dlist, Sb, rc);
    k_cubefin<<<NDMAX, 256, 0, stream>>>(Sb, dlist, rc);
    k_final<<<1, 256, 0, stream>>>(rc, mnum, dd, out);
}

// Round 11
// 142.480 us; speedup vs baseline: 1.3211x; 1.1245x over previous
//
#include <hip/hip_runtime.h>
#include <math.h>

#define VV 8192
#define DD 768
#define NDMAX 256

typedef __attribute__((ext_vector_type(8))) short bf16x8;
typedef __attribute__((ext_vector_type(4))) float f32x4;

// RNE float -> bf16 bits
__device__ inline ushort f2bf(float f) {
    uint u = __float_as_uint(f);
    uint r = (u + 0x7fffu + ((u >> 16) & 1u)) >> 16;
    return (ushort)r;
}
__device__ inline float bf2f(ushort h) { return __uint_as_float(((uint)h) << 16); }

__device__ inline void gload16(const ushort* g, ushort* l) {
    __builtin_amdgcn_global_load_lds(
        (const __attribute__((address_space(1))) void*)g,
        (__attribute__((address_space(3))) void*)l, 16, 0, 0);
}

// ---------------------------------------------------------------------------
// k_normpack: L2-normalize rows (fp64 norm accum) -> xh/xl (bf16 hi/lo split)
// + norms[r]. Also zeroes rc, dlist, dcount.
// ---------------------------------------------------------------------------
__global__ __launch_bounds__(256) void k_normpack(const float* __restrict__ t,
                                                  float* __restrict__ norms,
                                                  ushort* __restrict__ xh,
                                                  ushort* __restrict__ xl,
                                                  float* __restrict__ rc,
                                                  int* __restrict__ dlist,
                                                  int* __restrict__ dcount) {
    int r = blockIdx.x;
    const float* tr = t + (size_t)r * DD;
    int tid = threadIdx.x;
    float v0 = tr[tid], v1 = tr[tid + 256], v2 = tr[tid + 512];
    double s = (double)v0 * v0 + (double)v1 * v1 + (double)v2 * v2;
#pragma unroll
    for (int o = 32; o > 0; o >>= 1) s += __shfl_down(s, o, 64);
    __shared__ double wsum[4];
    int lane = tid & 63, w = tid >> 6;
    if (lane == 0) wsum[w] = s;
    __syncthreads();
    double tot = wsum[0] + wsum[1] + wsum[2] + wsum[3];
    float norm = fmaxf((float)sqrt(tot), 1e-12f);
    if (tid == 0) {
        norms[r] = norm;
        rc[r] = 0.f;
    }
    if (r == 0) {
        dlist[tid] = -1;
        if (tid == 0) *dcount = 0;
    }
    size_t base = (size_t)r * DD;
#pragma unroll
    for (int q = 0; q < 3; ++q) {
        int k = tid + q * 256;
        float v = (q == 0 ? v0 : (q == 1 ? v1 : v2)) / norm;
        ushort h = f2bf(v);
        xh[base + k] = h;
        xl[base + k] = f2bf(v - bf2f(h));
    }
}

// ---------------------------------------------------------------------------
// k_colsumA / k_colsumB: atomic-free two-stage column sum of x = fp32(t/norm)
// in fp64. Stage A: 256 blocks x 32 rows -> gp[b][k] partials (fixed order).
// Stage B: 768 threads sum gp[0..255][k] in fixed b-order -> g[k].
// Fully deterministic (the old atomic version wasn't even that).
// ---------------------------------------------------------------------------
__global__ __launch_bounds__(256) void k_colsumA(const float* __restrict__ t,
                                                 const float* __restrict__ norms,
                                                 double* __restrict__ gp) {
    int k = threadIdx.x;
    int r0 = blockIdx.x * 32;
    double s0 = 0.0, s1 = 0.0, s2 = 0.0;
    for (int r = r0; r < r0 + 32; ++r) {
        const float* tr = t + (size_t)r * DD;
        float nrm = norms[r];
        s0 += (double)(tr[k] / nrm);
        s1 += (double)(tr[k + 256] / nrm);
        s2 += (double)(tr[k + 512] / nrm);
    }
    double* gb = gp + (size_t)blockIdx.x * DD;
    gb[k] = s0;
    gb[k + 256] = s1;
    gb[k + 512] = s2;
}

__global__ __launch_bounds__(256) void k_colsumB(const double* __restrict__ gp,
                                                 double* __restrict__ g) {
    int col = blockIdx.x * 256 + threadIdx.x;
    double s = 0.0;
    for (int b = 0; b < 256; ++b) s += gp[(size_t)b * DD + col];
    g[col] = s;
}

// ---------------------------------------------------------------------------
// k_mean: mnum[r] = x_r.g - x_r.x_r (fp64); dd[r] = x_r.x_r. Exact mean
// path -- numerically deadly, do not approximate. Danger-row selection
// fused here (atomic compaction; slot order irrelevant).
// ---------------------------------------------------------------------------
__global__ __launch_bounds__(256) void k_mean(const float* __restrict__ t,
                                              const float* __restrict__ norms,
                                              const double* __restrict__ g,
                                              double* __restrict__ mnum,
                                              double* __restrict__ dd,
                                              int* __restrict__ dlist,
                                              int* __restrict__ dcount) {
    int r = blockIdx.x * 4 + (threadIdx.x >> 6);
    int lane = threadIdx.x & 63;
    const float* tr = t + (size_t)r * DD;
    float nrm = norms[r];
    double xg = 0.0, xx = 0.0;
#pragma unroll
    for (int k = lane; k < DD; k += 64) {
        float xf = tr[k] / nrm;
        double xv = (double)xf;
        xg += xv * g[k];
        xx += xv * xv;
    }
#pragma unroll
    for (int o = 32; o > 0; o >>= 1) {
        xg += __shfl_down(xg, o, 64);
        xx += __shfl_down(xx, o, 64);
    }
    if (lane == 0) {
        double m = xg - xx;
        mnum[r] = m;
        dd[r] = xx;
        if (fabs(m / 8191.0 + 1e-6) < 1e-5) {
            int pos = atomicAdd(dcount, 1);
            if (pos < NDMAX) dlist[pos] = r;
        }
    }
}

// ---------------------------------------------------------------------------
// k_cube: 128x128-tile bf16 MFMA pass, BK=32, triple-buffered staging with
// prefetch distance 2 and counted vmcnt(4) + raw s_barrier. 256 threads
// (4 waves 2Mx2N, per-wave 64x64), LDS 48 KiB -> 3 blocks/CU.
// LDS [128][32] bf16 per buffer; read-slot swizzle li4^((l15>>1)&3)
// (measured conflict-free); staged via global_load_lds w=16 with
// pre-swizzled per-lane source, linear dest.
// Grid 2464, uniform blocks (24 K-steps):
//  - bids 0..383: strip-partial (seg x rowpanel x colpanel): danger rows
//    (gathered) x 128 cols -> store partial S into Sb (no cube).
//  - bids 384..2463: big triangle tiles (hh only), BAND-MAJOR traversal
//    (8-bi-row bands, bj-sweep within band) so each XCD chunk keeps its 8
//    A-panels L2-resident and reuses each B-panel x8 -> L2-miss traffic /8.
//    2080 = 8*260 bijective XCD chunking; cube + row/col sums via symmetry.
// ---------------------------------------------------------------------------
__global__ __launch_bounds__(256, 3) void k_cube(const ushort* __restrict__ xh,
                                                 const ushort* __restrict__ xl,
                                                 const int* __restrict__ dlist,
                                                 float* __restrict__ Sb,
                                                 float* __restrict__ rc) {
    __shared__ ushort As0[4096], As1[4096], As2[4096];
    __shared__ ushort Bs0[4096], Bs1[4096], Bs2[4096];

    const int bid = blockIdx.x;
    const int tid = threadIdx.x;
    const int lane = tid & 63;
    const int wid = tid >> 6;
    const int l15 = lane & 15, li4 = lane >> 4;
    const int wm = wid >> 1, wn = wid & 1;

    const bool strip = (bid < 384);
    int bi = 0, bj = 0, seg = 0, rp = 0, cp = 0;
    if (strip) {
        seg = bid >> 7;
        int rem = bid & 127;
        rp = rem >> 6;
        cp = rem & 63;
    } else {
        int idx = bid - 384;
        int wg = (idx & 7) * 260 + (idx >> 3);  // XCD-bijective (2080 = 8*260)
        // band-major decode: band b (bi in [8b,8b+8)), bj-sweep, col height
        // h = min(8, cc+1); band sizes 484-64b sum to 2080.
        int b = 0, cnt = 484;
        while (wg >= cnt) { wg -= cnt; ++b; cnt -= 64; }
        int cc = 0, h = 1;
        while (wg >= h) { wg -= h; ++cc; h = (cc < 7) ? cc + 1 : 8; }
        bi = 8 * b + wg;
        bj = 8 * b + cc;
    }
    const ushort* XA = strip ? ((seg == 1) ? xl : xh) : xh;
    const ushort* XB = strip ? ((seg == 2) ? xl : xh) : xh;

    // staging descriptors: 2 gloads/thread per matrix per K-step
    int asrc[2], bsrc[2], ldst[2];
#pragma unroll
    for (int j = 0; j < 2; ++j) {
        int li = tid + j * 256;                    // 0..511
        int row = li >> 2;                         // 0..127
        int sl = ((li & 3) ^ ((li >> 3) & 3)) * 8; // pre-swizzled source slot
        int ar = strip ? dlist[rp * 128 + row] : (bi * 128 + row);
        if (ar < 0) ar = 0;
        int br = strip ? (cp * 128 + row) : (bj * 128 + row);
        asrc[j] = ar * DD + sl;
        bsrc[j] = br * DD + sl;
        ldst[j] = li * 8;                          // linear LDS dest (ushorts)
    }

    const int swz = (li4 ^ ((l15 >> 1) & 3)) << 3;
    const int aoff = (wm * 64 + l15) * 32 + swz;
    const int boff = (wn * 64 + l15) * 32 + swz;

    f32x4 acc[4][4];
#pragma unroll
    for (int f = 0; f < 4; ++f)
#pragma unroll
        for (int n = 0; n < 4; ++n) acc[f][n] = (f32x4){0.f, 0.f, 0.f, 0.f};

#define STG(AW, BW, KT)                                  \
    do {                                                 \
        const int kq_ = (KT) * 32;                       \
        gload16(XA + asrc[0] + kq_, (AW) + ldst[0]);     \
        gload16(XB + bsrc[0] + kq_, (BW) + ldst[0]);     \
        gload16(XA + asrc[1] + kq_, (AW) + ldst[1]);     \
        gload16(XB + bsrc[1] + kq_, (BW) + ldst[1]);     \
    } while (0)

#define COMPUTE(AR, BR)                                                     \
    do {                                                                    \
        bf16x8 av[4], bv[4];                                                \
        _Pragma("unroll") for (int f = 0; f < 4; ++f) {                     \
            av[f] = *(const bf16x8*)((AR) + aoff + f * 512);                \
            bv[f] = *(const bf16x8*)((BR) + boff + f * 512);                \
        }                                                                   \
        _Pragma("unroll") for (int f = 0; f < 4; ++f)                       \
            _Pragma("unroll") for (int n = 0; n < 4; ++n)                   \
                acc[f][n] = __builtin_amdgcn_mfma_f32_16x16x32_bf16(        \
                    av[f], bv[n], acc[f][n], 0, 0, 0);                      \
    } while (0)

#define VMW4() asm volatile("s_waitcnt vmcnt(4)" ::: "memory")
#define VMW0() asm volatile("s_waitcnt vmcnt(0)" ::: "memory")
#define RBAR() asm volatile("s_barrier" ::: "memory")

    // prologue: stage steps 0 and 1
    STG(As0, Bs0, 0);
    STG(As1, Bs1, 1);
    VMW4(); RBAR();  // step-0 loads landed

    // main loop: steps 0..20 (7 triples), each stages t+2, waits vmcnt(4)
    for (int tb = 0; tb < 21; tb += 3) {
        STG(As2, Bs2, tb + 2);
        COMPUTE(As0, Bs0);
        VMW4(); RBAR();
        STG(As0, Bs0, tb + 3);
        COMPUTE(As1, Bs1);
        VMW4(); RBAR();
        STG(As1, Bs1, tb + 4);
        COMPUTE(As2, Bs2);
        VMW4(); RBAR();
    }
    // t=21: stage 23 -> buf2; t=22, t=23 drain
    STG(As2, Bs2, 23);
    COMPUTE(As0, Bs0);
    VMW4(); RBAR();
    COMPUTE(As1, Bs1);
    VMW0(); RBAR();
    COMPUTE(As2, Bs2);
#undef STG
#undef COMPUTE
#undef VMW4
#undef VMW0
#undef RBAR

    if (strip) {
        // store partial S (f32) by danger slot; finish pass cubes later
#pragma unroll
        for (int f = 0; f < 4; ++f)
#pragma unroll
            for (int n = 0; n < 4; ++n)
#pragma unroll
                for (int r = 0; r < 4; ++r) {
                    int slot = seg * 256 + rp * 128 + wm * 64 + f * 16 + li4 * 4 + r;
                    int col = cp * 128 + wn * 64 + n * 16 + l15;
                    Sb[((size_t)slot << 13) + col] = acc[f][n][r];
                }
        return;
    }

    // big-tile epilogue: cube, skip diag, row + col (symmetry) sums
    const bool dblk = (bi == bj);
    const int R0 = bi * 128, C0 = bj * 128;
    float rsum[4][4], csum[4];
#pragma unroll
    for (int n = 0; n < 4; ++n) csum[n] = 0.f;
#pragma unroll
    for (int f = 0; f < 4; ++f)
#pragma unroll
        for (int r = 0; r < 4; ++r) rsum[f][r] = 0.f;
#pragma unroll
    for (int f = 0; f < 4; ++f)
#pragma unroll
        for (int n = 0; n < 4; ++n)
#pragma unroll
            for (int r = 0; r < 4; ++r) {
                float s = acc[f][n][r];
                float c = s * s * s;
                int ri = wm * 64 + f * 16 + li4 * 4 + r;
                int cj = wn * 64 + n * 16 + l15;
                if (dblk && ri == cj) c = 0.f;
                rsum[f][r] += c;
                csum[n] += c;
            }
    // row side: reduce across the 16 col-lanes (l15)
#pragma unroll
    for (int o = 1; o < 16; o <<= 1)
#pragma unroll
        for (int f = 0; f < 4; ++f)
#pragma unroll
            for (int r = 0; r < 4; ++r)
                rsum[f][r] += __shfl_xor(rsum[f][r], o, 64);
    if (l15 == 0) {
#pragma unroll
        for (int f = 0; f < 4; ++f)
#pragma unroll
            for (int r = 0; r < 4; ++r)
                atomicAdd(&rc[R0 + wm * 64 + f * 16 + li4 * 4 + r], rsum[f][r]);
    }
    // col side (rows bj*.. of S by symmetry; off-diag blocks only)
    if (!dblk) {
#pragma unroll
        for (int o = 16; o < 64; o <<= 1)
#pragma unroll
            for (int n = 0; n < 4; ++n) csum[n] += __shfl_xor(csum[n], o, 64);
        if (li4 == 0) {
#pragma unroll
            for (int n = 0; n < 4; ++n)
                atomicAdd(&rc[C0 + wn * 64 + n * 16 + l15], csum[n]);
        }
    }
}

// ---------------------------------------------------------------------------
// k_cubefin: per danger slot, correction = sum_c [(s0+s1+s2)^3 - s0^3]
// (skip c == drow; s0 bitwise-equals the big pass's hh value, so the
// subtraction exactly removes the hh-cube already in rc).
// ---------------------------------------------------------------------------
__global__ __launch_bounds__(256) void k_cubefin(const float* __restrict__ Sb,
                                                 const int* __restrict__ dlist,
                                                 float* __restrict__ rc) {
    const int slot = blockIdx.x;
    const int drow = dlist[slot];
    if (drow < 0) return;
    const int tid = threadIdx.x;
    const float* s0p = Sb + ((size_t)slot << 13);
    const float* s1p = Sb + ((size_t)(256 + slot) << 13);
    const float* s2p = Sb + ((size_t)(512 + slot) << 13);
    float sum = 0.f;
    for (int c = tid; c < VV; c += 256) {
        float s0 = s0p[c];
        float sf = s0 + s1p[c] + s2p[c];
        float d = sf * sf * sf - s0 * s0 * s0;
        if (c == drow) d = 0.f;
        sum += d;
    }
    __shared__ float red[256];
    red[tid] = sum;
    __syncthreads();
    for (int o = 128; o > 0; o >>= 1) {
        if (tid < o) red[tid] += red[tid + o];
        __syncthreads();
    }
    if (tid == 0) atomicAdd(&rc[drow], red[0]);
}

// ---------------------------------------------------------------------------
// k_final: out = collapse + 0.2 * sum_i rc_i / (mnum_i/8191 + 1e-6)
// ---------------------------------------------------------------------------
__global__ __launch_bounds__(256) void k_final(const float* __restrict__ rc,
                                               const double* __restrict__ mnum,
                                               const double* __restrict__ dd,
                                               float* __restrict__ out) {
    int tid = threadIdx.x;
    double acc = 0.0, col = 0.0;
    for (int r = tid; r < VV; r += 256) {
        double m = mnum[r] / 8191.0 + 1e-6;
        acc += (double)rc[r] / m;
        double dm = dd[r] - 1.0;
        col += dm * dm;
    }
    __shared__ double sa[256], sc[256];
    sa[tid] = acc;
    sc[tid] = col;
    __syncthreads();
    for (int o = 128; o > 0; o >>= 1) {
        if (tid < o) {
            sa[tid] += sa[tid + o];
            sc[tid] += sc[tid + o];
        }
        __syncthreads();
    }
    if (tid == 0) out[0] = (float)(sc[0] + 0.2 * sa[0]);
}

// ---------------------------------------------------------------------------
extern "C" void kernel_launch(void* const* d_in, const int* in_sizes, int n_in,
                              void* d_out, int out_size, void* d_ws, size_t ws_size,
                              hipStream_t stream) {
    const float* t = (const float*)d_in[0];
    float* out = (float*)d_out;

    char* ws = (char*)d_ws;
    float* Sb = (float*)ws;  // 3*256*8192*4B = 24 MB
    size_t off = (size_t)VV * DD * sizeof(float);  // keep 25.2 MB region
    ushort* xh = (ushort*)(ws + off); off += (size_t)VV * DD * sizeof(ushort);
    ushort* xl = (ushort*)(ws + off); off += (size_t)VV * DD * sizeof(ushort);
    double* g = (double*)(ws + off);  off += DD * sizeof(double);
    double* mnum = (double*)(ws + off); off += VV * sizeof(double);
    double* dd = (double*)(ws + off);  off += VV * sizeof(double);
    float* rc = (float*)(ws + off);    off += VV * sizeof(float);
    int* dlist = (int*)(ws + off);     off += NDMAX * sizeof(int);
    int* dcount = (int*)(ws + off);    off += sizeof(int) + 60;  // pad
    float* norms = (float*)(ws + off); off += VV * sizeof(float);
    double* gp = (double*)(ws + off);  off += (size_t)256 * DD * sizeof(double);

    k_normpack<<<VV, 256, 0, stream>>>(t, norms, xh, xl, rc, dlist, dcount);
    k_colsumA<<<256, 256, 0, stream>>>(t, norms, gp);
    k_colsumB<<<3, 256, 0, stream>>>(gp, g);
    k_mean<<<VV / 4, 256, 0, stream>>>(t, norms, g, mnum, dd, dlist, dcount);
    k_cube<<<2464, 256, 0, stream>>>(xh, xl, dlist, Sb, rc);
    k_cubefin<<<NDMAX, 256, 0, stream>>>(Sb, dlist, rc);
    k_final<<<1, 256, 0, stream>>>(rc, mnum, dd, out);
}

// Round 12
// 133.540 us; speedup vs baseline: 1.4095x; 1.0669x over previous
//
#include <hip/hip_runtime.h>
#include <math.h>

#define VV 8192
#define DD 768
#define NDMAX 256

typedef __attribute__((ext_vector_type(8))) short bf16x8;
typedef __attribute__((ext_vector_type(4))) float f32x4;

// RNE float -> bf16 bits
__device__ inline ushort f2bf(float f) {
    uint u = __float_as_uint(f);
    uint r = (u + 0x7fffu + ((u >> 16) & 1u)) >> 16;
    return (ushort)r;
}
__device__ inline float bf2f(ushort h) { return __uint_as_float(((uint)h) << 16); }

__device__ inline void gload16(const ushort* g, ushort* l) {
    __builtin_amdgcn_global_load_lds(
        (const __attribute__((address_space(1))) void*)g,
        (__attribute__((address_space(3))) void*)l, 16, 0, 0);
}

// ---------------------------------------------------------------------------
// k_normpack: L2-normalize rows (fp64 norm accum) -> xh/xl (bf16 hi/lo split)
// + norms[r]. Also zeroes rc, dlist, dcount.
// ---------------------------------------------------------------------------
__global__ __launch_bounds__(256) void k_normpack(const float* __restrict__ t,
                                                  float* __restrict__ norms,
                                                  ushort* __restrict__ xh,
                                                  ushort* __restrict__ xl,
                                                  float* __restrict__ rc,
                                                  int* __restrict__ dlist,
                                                  int* __restrict__ dcount) {
    int r = blockIdx.x;
    const float* tr = t + (size_t)r * DD;
    int tid = threadIdx.x;
    float v0 = tr[tid], v1 = tr[tid + 256], v2 = tr[tid + 512];
    double s = (double)v0 * v0 + (double)v1 * v1 + (double)v2 * v2;
#pragma unroll
    for (int o = 32; o > 0; o >>= 1) s += __shfl_down(s, o, 64);
    __shared__ double wsum[4];
    int lane = tid & 63, w = tid >> 6;
    if (lane == 0) wsum[w] = s;
    __syncthreads();
    double tot = wsum[0] + wsum[1] + wsum[2] + wsum[3];
    float norm = fmaxf((float)sqrt(tot), 1e-12f);
    if (tid == 0) {
        norms[r] = norm;
        rc[r] = 0.f;
    }
    if (r == 0) {
        dlist[tid] = -1;
        if (tid == 0) *dcount = 0;
    }
    size_t base = (size_t)r * DD;
#pragma unroll
    for (int q = 0; q < 3; ++q) {
        int k = tid + q * 256;
        float v = (q == 0 ? v0 : (q == 1 ? v1 : v2)) / norm;
        ushort h = f2bf(v);
        xh[base + k] = h;
        xl[base + k] = f2bf(v - bf2f(h));
    }
}

// ---------------------------------------------------------------------------
// k_colsumA / k_colsumB: atomic-free two-stage column sum of x = fp32(t/norm)
// in fp64, deterministic.
// ---------------------------------------------------------------------------
__global__ __launch_bounds__(256) void k_colsumA(const float* __restrict__ t,
                                                 const float* __restrict__ norms,
                                                 double* __restrict__ gp) {
    int k = threadIdx.x;
    int r0 = blockIdx.x * 32;
    double s0 = 0.0, s1 = 0.0, s2 = 0.0;
    for (int r = r0; r < r0 + 32; ++r) {
        const float* tr = t + (size_t)r * DD;
        float nrm = norms[r];
        s0 += (double)(tr[k] / nrm);
        s1 += (double)(tr[k + 256] / nrm);
        s2 += (double)(tr[k + 512] / nrm);
    }
    double* gb = gp + (size_t)blockIdx.x * DD;
    gb[k] = s0;
    gb[k + 256] = s1;
    gb[k + 512] = s2;
}

__global__ __launch_bounds__(256) void k_colsumB(const double* __restrict__ gp,
                                                 double* __restrict__ g) {
    __shared__ double red[8][32];
    int c = threadIdx.x & 31, part = threadIdx.x >> 5;
    int col = blockIdx.x * 32 + c;
    double s = 0.0;
    for (int b = part * 32; b < part * 32 + 32; ++b)
        s += gp[(size_t)b * DD + col];
    red[part][c] = s;
    __syncthreads();
    if (part == 0) {
        double tt = 0.0;
        for (int p = 0; p < 8; ++p) tt += red[p][c];
        g[col] = tt;
    }
}

// ---------------------------------------------------------------------------
// k_mean: mnum[r] = x_r.g - x_r.x_r (fp64); dd[r] = x_r.x_r. Exact mean
// path -- numerically deadly, do not approximate. Danger-row selection
// fused (atomic compaction; slot order irrelevant).
// ---------------------------------------------------------------------------
__global__ __launch_bounds__(256) void k_mean(const float* __restrict__ t,
                                              const float* __restrict__ norms,
                                              const double* __restrict__ g,
                                              double* __restrict__ mnum,
                                              double* __restrict__ dd,
                                              int* __restrict__ dlist,
                                              int* __restrict__ dcount) {
    int r = blockIdx.x * 4 + (threadIdx.x >> 6);
    int lane = threadIdx.x & 63;
    const float* tr = t + (size_t)r * DD;
    float nrm = norms[r];
    double xg = 0.0, xx = 0.0;
#pragma unroll
    for (int k = lane; k < DD; k += 64) {
        float xf = tr[k] / nrm;
        double xv = (double)xf;
        xg += xv * g[k];
        xx += xv * xv;
    }
#pragma unroll
    for (int o = 32; o > 0; o >>= 1) {
        xg += __shfl_down(xg, o, 64);
        xx += __shfl_down(xx, o, 64);
    }
    if (lane == 0) {
        double m = xg - xx;
        mnum[r] = m;
        dd[r] = xx;
        if (fabs(m / 8191.0 + 1e-6) < 1e-5) {
            int pos = atomicAdd(dcount, 1);
            if (pos < NDMAX) dlist[pos] = r;
        }
    }
}

// ---------------------------------------------------------------------------
// k_cube: 128x256-tile bf16 MFMA pass (4 waves 2Mx2N, per-wave 64x128 =
// 4x8 frags -> 12 LDS reads feed 32 MFMA: 25-30% less LDS traffic/FLOP than
// the 64x64-per-wave shape; LDS was the measured binding pipe at r11).
// BK=32, triple-buffered, prefetch distance 2, counted vmcnt(6) + raw
// s_barrier. LDS 72 KiB -> 2 blocks/CU. [rows][32] bf16 layout, read-slot
// swizzle li4^((l15>>1)&3) (measured conflict-free), global_load_lds w=16
// with pre-swizzled per-lane source, linear dest.
// Grid 1248, uniform blocks (24 K-steps):
//  - bids 0..191: strip-partial (3 seg x 2 rowpanel x 32 colchunk): danger
//    rows (gathered) x 256 cols -> store partial S into Sb (no cube).
//  - bids 192..1247: triangle tiles (hh only): 128-row x 256-col tiles,
//    i <= 2j+1; tiles with bi in {2bj,2bj+1} lie inside the diagonal
//    256-block -> row-side only + ri==cj skip (each in-block ordered pair
//    covered exactly once); strictly-upper tiles (bi <= 2bj-1) add col-side
//    by symmetry. j-major order + 8x132 bijective XCD chunks (B-panel L2
//    reuse within a chunk).
// ---------------------------------------------------------------------------
__global__ __launch_bounds__(256, 2) void k_cube(const ushort* __restrict__ xh,
                                                 const ushort* __restrict__ xl,
                                                 const int* __restrict__ dlist,
                                                 float* __restrict__ Sb,
                                                 float* __restrict__ rc) {
    __shared__ ushort As0[4096], As1[4096], As2[4096];  // 128x32 bf16 each
    __shared__ ushort Bs0[8192], Bs1[8192], Bs2[8192];  // 256x32 bf16 each

    const int bid = blockIdx.x;
    const int tid = threadIdx.x;
    const int lane = tid & 63;
    const int wid = tid >> 6;
    const int l15 = lane & 15, li4 = lane >> 4;
    const int wm = wid >> 1, wn = wid & 1;  // 2M x 2N; per-wave 64 x 128

    const bool strip = (bid < 192);
    int bi = 0, bj = 0, seg = 0, rp = 0, cp = 0;
    if (strip) {
        seg = bid >> 6;
        int rem = bid & 63;
        rp = rem >> 5;
        cp = rem & 31;
    } else {
        int idx = bid - 192;
        int wg = (idx & 7) * 132 + (idx >> 3);  // XCD-bijective (1056 = 8*132)
        int j = 0;
        while (wg >= 2 * j + 2) { wg -= 2 * j + 2; ++j; }  // j-major, i inner
        bi = wg;   // 0..2j+1
        bj = j;
    }
    const ushort* XA = strip ? ((seg == 1) ? xl : xh) : xh;
    const ushort* XB = strip ? ((seg == 2) ? xl : xh) : xh;

    // staging descriptors: A 2 gloads/thread, B 4 gloads/thread per K-step
    int asrc[2], bsrc[4], lda_[2], ldb_[4];
#pragma unroll
    for (int j = 0; j < 2; ++j) {
        int li = tid + j * 256;                    // 0..511
        int row = li >> 2;                         // 0..127
        int sl = ((li & 3) ^ ((li >> 3) & 3)) * 8; // pre-swizzled source slot
        int ar = strip ? dlist[rp * 128 + row] : (bi * 128 + row);
        if (ar < 0) ar = 0;
        asrc[j] = ar * DD + sl;
        lda_[j] = li * 8;
    }
#pragma unroll
    for (int j = 0; j < 4; ++j) {
        int li = tid + j * 256;                    // 0..1023
        int row = li >> 2;                         // 0..255
        int sl = ((li & 3) ^ ((li >> 3) & 3)) * 8;
        int br = strip ? (cp * 256 + row) : (bj * 256 + row);
        bsrc[j] = br * DD + sl;
        ldb_[j] = li * 8;
    }

    const int swz = (li4 ^ ((l15 >> 1) & 3)) << 3;
    const int aoff = (wm * 64 + l15) * 32 + swz;
    const int boff = (wn * 128 + l15) * 32 + swz;

    f32x4 acc[4][8];
#pragma unroll
    for (int f = 0; f < 4; ++f)
#pragma unroll
        for (int n = 0; n < 8; ++n) acc[f][n] = (f32x4){0.f, 0.f, 0.f, 0.f};

#define STG(AW, BW, KT)                                  \
    do {                                                 \
        const int kq_ = (KT) * 32;                       \
        gload16(XA + asrc[0] + kq_, (AW) + lda_[0]);     \
        gload16(XA + asrc[1] + kq_, (AW) + lda_[1]);     \
        gload16(XB + bsrc[0] + kq_, (BW) + ldb_[0]);     \
        gload16(XB + bsrc[1] + kq_, (BW) + ldb_[1]);     \
        gload16(XB + bsrc[2] + kq_, (BW) + ldb_[2]);     \
        gload16(XB + bsrc[3] + kq_, (BW) + ldb_[3]);     \
    } while (0)

#define COMPUTE(AR, BR)                                                     \
    do {                                                                    \
        bf16x8 av[4], bv[8];                                                \
        _Pragma("unroll") for (int f = 0; f < 4; ++f)                       \
            av[f] = *(const bf16x8*)((AR) + aoff + f * 512);                \
        _Pragma("unroll") for (int n = 0; n < 8; ++n)                       \
            bv[n] = *(const bf16x8*)((BR) + boff + n * 512);                \
        _Pragma("unroll") for (int f = 0; f < 4; ++f)                       \
            _Pragma("unroll") for (int n = 0; n < 8; ++n)                   \
                acc[f][n] = __builtin_amdgcn_mfma_f32_16x16x32_bf16(        \
                    av[f], bv[n], acc[f][n], 0, 0, 0);                      \
    } while (0)

#define VMW6() asm volatile("s_waitcnt vmcnt(6)" ::: "memory")
#define VMW0() asm volatile("s_waitcnt vmcnt(0)" ::: "memory")
#define RBAR() asm volatile("s_barrier" ::: "memory")

    // prologue: stage steps 0 and 1
    STG(As0, Bs0, 0);
    STG(As1, Bs1, 1);
    VMW6(); RBAR();  // step-0 loads landed

    // main loop: steps 0..20 (7 triples), each stages t+2, waits vmcnt(6)
    for (int tb = 0; tb < 21; tb += 3) {
        STG(As2, Bs2, tb + 2);
        COMPUTE(As0, Bs0);
        VMW6(); RBAR();
        STG(As0, Bs0, tb + 3);
        COMPUTE(As1, Bs1);
        VMW6(); RBAR();
        STG(As1, Bs1, tb + 4);
        COMPUTE(As2, Bs2);
        VMW6(); RBAR();
    }
    // t=21: stage 23 -> buf2; t=22, t=23 drain
    STG(As2, Bs2, 23);
    COMPUTE(As0, Bs0);
    VMW6(); RBAR();
    COMPUTE(As1, Bs1);
    VMW0(); RBAR();
    COMPUTE(As2, Bs2);
#undef STG
#undef COMPUTE
#undef VMW6
#undef VMW0
#undef RBAR

    if (strip) {
        // store partial S (f32) by danger slot; finish pass cubes later
#pragma unroll
        for (int f = 0; f < 4; ++f)
#pragma unroll
            for (int n = 0; n < 8; ++n)
#pragma unroll
                for (int r = 0; r < 4; ++r) {
                    int slot = seg * 256 + rp * 128 + wm * 64 + f * 16 + li4 * 4 + r;
                    int col = cp * 256 + wn * 128 + n * 16 + l15;
                    Sb[((size_t)slot << 13) + col] = acc[f][n][r];
                }
        return;
    }

    // triangle epilogue: cube; dtile (inside diagonal 256-block): row-only
    // with ri==cj skip; strictly-upper: row + col (symmetry) sums.
    const bool dtile = ((bi >> 1) == bj);
    const int R0 = bi * 128, C0 = bj * 256;
    float rsum[4][4], csum[8];
#pragma unroll
    for (int n = 0; n < 8; ++n) csum[n] = 0.f;
#pragma unroll
    for (int f = 0; f < 4; ++f)
#pragma unroll
        for (int r = 0; r < 4; ++r) rsum[f][r] = 0.f;
#pragma unroll
    for (int f = 0; f < 4; ++f)
#pragma unroll
        for (int n = 0; n < 8; ++n)
#pragma unroll
            for (int r = 0; r < 4; ++r) {
                float s = acc[f][n][r];
                float c = s * s * s;
                int ri = R0 + wm * 64 + f * 16 + li4 * 4 + r;
                int cj = C0 + wn * 128 + n * 16 + l15;
                if (dtile && ri == cj) c = 0.f;
                rsum[f][r] += c;
                csum[n] += c;
            }
    // row side: reduce across the 16 col-lanes (l15)
#pragma unroll
    for (int o = 1; o < 16; o <<= 1)
#pragma unroll
        for (int f = 0; f < 4; ++f)
#pragma unroll
            for (int r = 0; r < 4; ++r)
                rsum[f][r] += __shfl_xor(rsum[f][r], o, 64);
    if (l15 == 0) {
#pragma unroll
        for (int f = 0; f < 4; ++f)
#pragma unroll
            for (int r = 0; r < 4; ++r)
                atomicAdd(&rc[R0 + wm * 64 + f * 16 + li4 * 4 + r], rsum[f][r]);
    }
    // col side (rows C0.. of S by symmetry; strictly-upper tiles only)
    if (!dtile) {
#pragma unroll
        for (int o = 16; o < 64; o <<= 1)
#pragma unroll
            for (int n = 0; n < 8; ++n) csum[n] += __shfl_xor(csum[n], o, 64);
        if (li4 == 0) {
#pragma unroll
            for (int n = 0; n < 8; ++n)
                atomicAdd(&rc[C0 + wn * 128 + n * 16 + l15], csum[n]);
        }
    }
}

// ---------------------------------------------------------------------------
// k_cubefin: per danger slot, correction = sum_c [(s0+s1+s2)^3 - s0^3]
// (skip c == drow; s0 bitwise-equals the triangle pass's hh value).
// ---------------------------------------------------------------------------
__global__ __launch_bounds__(256) void k_cubefin(const float* __restrict__ Sb,
                                                 const int* __restrict__ dlist,
                                                 float* __restrict__ rc) {
    const int slot = blockIdx.x;
    const int drow = dlist[slot];
    if (drow < 0) return;
    const int tid = threadIdx.x;
    const float* s0p = Sb + ((size_t)slot << 13);
    const float* s1p = Sb + ((size_t)(256 + slot) << 13);
    const float* s2p = Sb + ((size_t)(512 + slot) << 13);
    float sum = 0.f;
    for (int c = tid; c < VV; c += 256) {
        float s0 = s0p[c];
        float sf = s0 + s1p[c] + s2p[c];
        float d = sf * sf * sf - s0 * s0 * s0;
        if (c == drow) d = 0.f;
        sum += d;
    }
    __shared__ float red[256];
    red[tid] = sum;
    __syncthreads();
    for (int o = 128; o > 0; o >>= 1) {
        if (tid < o) red[tid] += red[tid + o];
        __syncthreads();
    }
    if (tid == 0) atomicAdd(&rc[drow], red[0]);
}

// ---------------------------------------------------------------------------
// k_final: out = collapse + 0.2 * sum_i rc_i / (mnum_i/8191 + 1e-6)
// ---------------------------------------------------------------------------
__global__ __launch_bounds__(1024) void k_final(const float* __restrict__ rc,
                                                const double* __restrict__ mnum,
                                                const double* __restrict__ dd,
                                                float* __restrict__ out) {
    int tid = threadIdx.x;
    double acc = 0.0, col = 0.0;
    for (int r = tid; r < VV; r += 1024) {
        double m = mnum[r] / 8191.0 + 1e-6;
        acc += (double)rc[r] / m;
        double dm = dd[r] - 1.0;
        col += dm * dm;
    }
    __shared__ double sa[1024], sc[1024];
    sa[tid] = acc;
    sc[tid] = col;
    __syncthreads();
    for (int o = 512; o > 0; o >>= 1) {
        if (tid < o) {
            sa[tid] += sa[tid + o];
            sc[tid] += sc[tid + o];
        }
        __syncthreads();
    }
    if (tid == 0) out[0] = (float)(sc[0] + 0.2 * sa[0]);
}

// ---------------------------------------------------------------------------
extern "C" void kernel_launch(void* const* d_in, const int* in_sizes, int n_in,
                              void* d_out, int out_size, void* d_ws, size_t ws_size,
                              hipStream_t stream) {
    const float* t = (const float*)d_in[0];
    float* out = (float*)d_out;

    char* ws = (char*)d_ws;
    float* Sb = (float*)ws;  // 3*256*8192*4B = 24 MB
    size_t off = (size_t)VV * DD * sizeof(float);  // keep 25.2 MB region
    ushort* xh = (ushort*)(ws + off); off += (size_t)VV * DD * sizeof(ushort);
    ushort* xl = (ushort*)(ws + off); off += (size_t)VV * DD * sizeof(ushort);
    double* g = (double*)(ws + off);  off += DD * sizeof(double);
    double* mnum = (double*)(ws + off); off += VV * sizeof(double);
    double* dd = (double*)(ws + off);  off += VV * sizeof(double);
    float* rc = (float*)(ws + off);    off += VV * sizeof(float);
    int* dlist = (int*)(ws + off);     off += NDMAX * sizeof(int);
    int* dcount = (int*)(ws + off);    off += sizeof(int) + 60;  // pad
    float* norms = (float*)(ws + off); off += VV * sizeof(float);
    double* gp = (double*)(ws + off);  off += (size_t)256 * DD * sizeof(double);

    k_normpack<<<VV, 256, 0, stream>>>(t, norms, xh, xl, rc, dlist, dcount);
    k_colsumA<<<256, 256, 0, stream>>>(t, norms, gp);
    k_colsumB<<<24, 256, 0, stream>>>(gp, g);
    k_mean<<<VV / 4, 256, 0, stream>>>(t, norms, g, mnum, dd, dlist, dcount);
    k_cube<<<1248, 256, 0, stream>>>(xh, xl, dlist, Sb, rc);
    k_cubefin<<<NDMAX, 256, 0, stream>>>(Sb, dlist, rc);
    k_final<<<1, 1024, 0, stream>>>(rc, mnum, dd, out);
}

// Round 13
// 121.213 us; speedup vs baseline: 1.5529x; 1.1017x over previous
//
#include <hip/hip_runtime.h>
#include <math.h>

#define VV 8192
#define DD 768
#define NDMAX 256

typedef __attribute__((ext_vector_type(8))) short bf16x8;
typedef __attribute__((ext_vector_type(4))) float f32x4;

// RNE float -> bf16 bits
__device__ inline ushort f2bf(float f) {
    uint u = __float_as_uint(f);
    uint r = (u + 0x7fffu + ((u >> 16) & 1u)) >> 16;
    return (ushort)r;
}
__device__ inline float bf2f(ushort h) { return __uint_as_float(((uint)h) << 16); }

__device__ inline void gload16(const ushort* g, ushort* l) {
    __builtin_amdgcn_global_load_lds(
        (const __attribute__((address_space(1))) void*)g,
        (__attribute__((address_space(3))) void*)l, 16, 0, 0);
}

// ---------------------------------------------------------------------------
// k_normfused: per row -- L2-normalize (fp64 sumsq, bitwise-identical to the
// proven per-row code) -> xh/xl bf16 hi/lo split + norms[r]; PLUS fused
// column-sum partials of x = fp32(t/norm) in fp64 (replaces k_colsumA,
// saving a full 25-MB re-read of t). 512 blocks x 16 rows, 2-row ILP.
// Also zeroes rc, dlist, dcount.
// ---------------------------------------------------------------------------
__global__ __launch_bounds__(256) void k_normfused(const float* __restrict__ t,
                                                   float* __restrict__ norms,
                                                   ushort* __restrict__ xh,
                                                   ushort* __restrict__ xl,
                                                   double* __restrict__ gp,
                                                   float* __restrict__ rc,
                                                   int* __restrict__ dlist,
                                                   int* __restrict__ dcount) {
    const int tid = threadIdx.x;
    const int r0 = blockIdx.x * 16;
    if (tid < 16) rc[r0 + tid] = 0.f;
    if (blockIdx.x == 0) {
        dlist[tid] = -1;
        if (tid == 0) *dcount = 0;
    }
    __shared__ double wsum[2][4];
    const int lane = tid & 63, w = tid >> 6;
    double s0 = 0.0, s1 = 0.0, s2 = 0.0;
    for (int rr = 0; rr < 16; rr += 2) {
        const float* trA = t + (size_t)(r0 + rr) * DD;
        const float* trB = trA + DD;
        float a0 = trA[tid], a1 = trA[tid + 256], a2 = trA[tid + 512];
        float b0 = trB[tid], b1 = trB[tid + 256], b2 = trB[tid + 512];
        double sA = (double)a0 * a0 + (double)a1 * a1 + (double)a2 * a2;
        double sB = (double)b0 * b0 + (double)b1 * b1 + (double)b2 * b2;
#pragma unroll
        for (int o = 32; o > 0; o >>= 1) {
            sA += __shfl_down(sA, o, 64);
            sB += __shfl_down(sB, o, 64);
        }
        if (lane == 0) { wsum[0][w] = sA; wsum[1][w] = sB; }
        __syncthreads();
        float nA = fmaxf((float)sqrt(wsum[0][0] + wsum[0][1] + wsum[0][2] + wsum[0][3]), 1e-12f);
        float nB = fmaxf((float)sqrt(wsum[1][0] + wsum[1][1] + wsum[1][2] + wsum[1][3]), 1e-12f);
        __syncthreads();  // wsum reuse protection
        if (tid == 0) {
            norms[r0 + rr] = nA;
            norms[r0 + rr + 1] = nB;
        }
        size_t baseA = (size_t)(r0 + rr) * DD, baseB = baseA + DD;
        float xA0 = a0 / nA, xA1 = a1 / nA, xA2 = a2 / nA;
        float xB0 = b0 / nB, xB1 = b1 / nB, xB2 = b2 / nB;
        ushort h;
        h = f2bf(xA0); xh[baseA + tid] = h;       xl[baseA + tid] = f2bf(xA0 - bf2f(h));
        h = f2bf(xA1); xh[baseA + tid + 256] = h; xl[baseA + tid + 256] = f2bf(xA1 - bf2f(h));
        h = f2bf(xA2); xh[baseA + tid + 512] = h; xl[baseA + tid + 512] = f2bf(xA2 - bf2f(h));
        h = f2bf(xB0); xh[baseB + tid] = h;       xl[baseB + tid] = f2bf(xB0 - bf2f(h));
        h = f2bf(xB1); xh[baseB + tid + 256] = h; xl[baseB + tid + 256] = f2bf(xB1 - bf2f(h));
        h = f2bf(xB2); xh[baseB + tid + 512] = h; xl[baseB + tid + 512] = f2bf(xB2 - bf2f(h));
        // column partials, rows in sequential order (rr then rr+1)
        s0 += (double)xA0; s0 += (double)xB0;
        s1 += (double)xA1; s1 += (double)xB1;
        s2 += (double)xA2; s2 += (double)xB2;
    }
    double* gb = gp + (size_t)blockIdx.x * DD;
    gb[tid] = s0;
    gb[tid + 256] = s1;
    gb[tid + 512] = s2;
}

// ---------------------------------------------------------------------------
// k_colsumB: g[col] = sum of 512 block partials in fixed order (fp64,
// deterministic, atomic-free).
// ---------------------------------------------------------------------------
__global__ __launch_bounds__(256) void k_colsumB(const double* __restrict__ gp,
                                                 double* __restrict__ g) {
    __shared__ double red[8][32];
    int c = threadIdx.x & 31, part = threadIdx.x >> 5;
    int col = blockIdx.x * 32 + c;
    double s = 0.0;
    for (int b = part * 64; b < part * 64 + 64; ++b)
        s += gp[(size_t)b * DD + col];
    red[part][c] = s;
    __syncthreads();
    if (part == 0) {
        double tt = 0.0;
        for (int p = 0; p < 8; ++p) tt += red[p][c];
        g[col] = tt;
    }
}

// ---------------------------------------------------------------------------
// k_mean: mnum[r] = x_r.g - x_r.x_r (fp64); dd[r] = x_r.x_r. Exact mean
// path -- numerically deadly, do not approximate. Danger-row selection
// fused (atomic compaction; slot order irrelevant).
// ---------------------------------------------------------------------------
__global__ __launch_bounds__(256) void k_mean(const float* __restrict__ t,
                                              const float* __restrict__ norms,
                                              const double* __restrict__ g,
                                              double* __restrict__ mnum,
                                              double* __restrict__ dd,
                                              int* __restrict__ dlist,
                                              int* __restrict__ dcount) {
    int r = blockIdx.x * 4 + (threadIdx.x >> 6);
    int lane = threadIdx.x & 63;
    const float* tr = t + (size_t)r * DD;
    float nrm = norms[r];
    double xg = 0.0, xx = 0.0;
#pragma unroll
    for (int k = lane; k < DD; k += 64) {
        float xf = tr[k] / nrm;
        double xv = (double)xf;
        xg += xv * g[k];
        xx += xv * xv;
    }
#pragma unroll
    for (int o = 32; o > 0; o >>= 1) {
        xg += __shfl_down(xg, o, 64);
        xx += __shfl_down(xx, o, 64);
    }
    if (lane == 0) {
        double m = xg - xx;
        mnum[r] = m;
        dd[r] = xx;
        if (fabs(m / 8191.0 + 1e-6) < 1e-5) {
            int pos = atomicAdd(dcount, 1);
            if (pos < NDMAX) dlist[pos] = r;
        }
    }
}

// ---------------------------------------------------------------------------
// k_cube: 128x256-tile bf16 MFMA pass (4 waves 2Mx2N, per-wave 64x128).
// BK=32, triple-buffered, prefetch distance 2, counted vmcnt(6) + raw
// s_barrier. LDS 72 KiB -> 2 blocks/CU. [rows][32] bf16 layout, read-slot
// swizzle li4^((l15>>1)&3) (measured conflict-free), global_load_lds w=16
// with pre-swizzled per-lane source, linear dest.
// At r12's measured state this pass is at ~36% of the 16x16 MFMA ceiling --
// the structural plateau of compiler-scheduled HIP for this shape; left as-is.
// Grid 1248, uniform blocks (24 K-steps):
//  - bids 0..191: strip-partial (3 seg x 2 rowpanel x 32 colchunk): danger
//    rows (gathered) x 256 cols -> store partial S into Sb (no cube).
//    Whole-panel early-exit when the rowpanel is empty (compaction is
//    contiguous).
//  - bids 192..1247: triangle tiles (hh only): 128-row x 256-col, i <= 2j+1;
//    dtile (bi>>1==bj) -> row-side only + ri==cj skip; strictly-upper adds
//    col-side by symmetry. j-major + 8x132 bijective XCD chunks.
// ---------------------------------------------------------------------------
__global__ __launch_bounds__(256, 2) void k_cube(const ushort* __restrict__ xh,
                                                 const ushort* __restrict__ xl,
                                                 const int* __restrict__ dlist,
                                                 float* __restrict__ Sb,
                                                 float* __restrict__ rc) {
    __shared__ ushort As0[4096], As1[4096], As2[4096];  // 128x32 bf16 each
    __shared__ ushort Bs0[8192], Bs1[8192], Bs2[8192];  // 256x32 bf16 each

    const int bid = blockIdx.x;
    const int tid = threadIdx.x;
    const int lane = tid & 63;
    const int wid = tid >> 6;
    const int l15 = lane & 15, li4 = lane >> 4;
    const int wm = wid >> 1, wn = wid & 1;  // 2M x 2N; per-wave 64 x 128

    const bool strip = (bid < 192);
    int bi = 0, bj = 0, seg = 0, rp = 0, cp = 0;
    if (strip) {
        seg = bid >> 6;
        int rem = bid & 63;
        rp = rem >> 5;
        cp = rem & 31;
        if (dlist[rp * 128] < 0) return;  // empty rowpanel (contiguous fill)
    } else {
        int idx = bid - 192;
        int wg = (idx & 7) * 132 + (idx >> 3);  // XCD-bijective (1056 = 8*132)
        int j = 0;
        while (wg >= 2 * j + 2) { wg -= 2 * j + 2; ++j; }  // j-major, i inner
        bi = wg;   // 0..2j+1
        bj = j;
    }
    const ushort* XA = strip ? ((seg == 1) ? xl : xh) : xh;
    const ushort* XB = strip ? ((seg == 2) ? xl : xh) : xh;

    // staging descriptors: A 2 gloads/thread, B 4 gloads/thread per K-step
    int asrc[2], bsrc[4], lda_[2], ldb_[4];
#pragma unroll
    for (int j = 0; j < 2; ++j) {
        int li = tid + j * 256;                    // 0..511
        int row = li >> 2;                         // 0..127
        int sl = ((li & 3) ^ ((li >> 3) & 3)) * 8; // pre-swizzled source slot
        int ar = strip ? dlist[rp * 128 + row] : (bi * 128 + row);
        if (ar < 0) ar = 0;
        asrc[j] = ar * DD + sl;
        lda_[j] = li * 8;
    }
#pragma unroll
    for (int j = 0; j < 4; ++j) {
        int li = tid + j * 256;                    // 0..1023
        int row = li >> 2;                         // 0..255
        int sl = ((li & 3) ^ ((li >> 3) & 3)) * 8;
        int br = strip ? (cp * 256 + row) : (bj * 256 + row);
        bsrc[j] = br * DD + sl;
        ldb_[j] = li * 8;
    }

    const int swz = (li4 ^ ((l15 >> 1) & 3)) << 3;
    const int aoff = (wm * 64 + l15) * 32 + swz;
    const int boff = (wn * 128 + l15) * 32 + swz;

    f32x4 acc[4][8];
#pragma unroll
    for (int f = 0; f < 4; ++f)
#pragma unroll
        for (int n = 0; n < 8; ++n) acc[f][n] = (f32x4){0.f, 0.f, 0.f, 0.f};

#define STG(AW, BW, KT)                                  \
    do {                                                 \
        const int kq_ = (KT) * 32;                       \
        gload16(XA + asrc[0] + kq_, (AW) + lda_[0]);     \
        gload16(XA + asrc[1] + kq_, (AW) + lda_[1]);     \
        gload16(XB + bsrc[0] + kq_, (BW) + ldb_[0]);     \
        gload16(XB + bsrc[1] + kq_, (BW) + ldb_[1]);     \
        gload16(XB + bsrc[2] + kq_, (BW) + ldb_[2]);     \
        gload16(XB + bsrc[3] + kq_, (BW) + ldb_[3]);     \
    } while (0)

#define COMPUTE(AR, BR)                                                     \
    do {                                                                    \
        bf16x8 av[4], bv[8];                                                \
        _Pragma("unroll") for (int f = 0; f < 4; ++f)                       \
            av[f] = *(const bf16x8*)((AR) + aoff + f * 512);                \
        _Pragma("unroll") for (int n = 0; n < 8; ++n)                       \
            bv[n] = *(const bf16x8*)((BR) + boff + n * 512);                \
        _Pragma("unroll") for (int f = 0; f < 4; ++f)                       \
            _Pragma("unroll") for (int n = 0; n < 8; ++n)                   \
                acc[f][n] = __builtin_amdgcn_mfma_f32_16x16x32_bf16(        \
                    av[f], bv[n], acc[f][n], 0, 0, 0);                      \
    } while (0)

#define VMW6() asm volatile("s_waitcnt vmcnt(6)" ::: "memory")
#define VMW0() asm volatile("s_waitcnt vmcnt(0)" ::: "memory")
#define RBAR() asm volatile("s_barrier" ::: "memory")

    // prologue: stage steps 0 and 1
    STG(As0, Bs0, 0);
    STG(As1, Bs1, 1);
    VMW6(); RBAR();  // step-0 loads landed

    // main loop: steps 0..20 (7 triples), each stages t+2, waits vmcnt(6)
    for (int tb = 0; tb < 21; tb += 3) {
        STG(As2, Bs2, tb + 2);
        COMPUTE(As0, Bs0);
        VMW6(); RBAR();
        STG(As0, Bs0, tb + 3);
        COMPUTE(As1, Bs1);
        VMW6(); RBAR();
        STG(As1, Bs1, tb + 4);
        COMPUTE(As2, Bs2);
        VMW6(); RBAR();
    }
    // t=21: stage 23 -> buf2; t=22, t=23 drain
    STG(As2, Bs2, 23);
    COMPUTE(As0, Bs0);
    VMW6(); RBAR();
    COMPUTE(As1, Bs1);
    VMW0(); RBAR();
    COMPUTE(As2, Bs2);
#undef STG
#undef COMPUTE
#undef VMW6
#undef VMW0
#undef RBAR

    if (strip) {
        // store partial S (f32) by danger slot; finish pass cubes later
#pragma unroll
        for (int f = 0; f < 4; ++f)
#pragma unroll
            for (int n = 0; n < 8; ++n)
#pragma unroll
                for (int r = 0; r < 4; ++r) {
                    int slot = seg * 256 + rp * 128 + wm * 64 + f * 16 + li4 * 4 + r;
                    int col = cp * 256 + wn * 128 + n * 16 + l15;
                    Sb[((size_t)slot << 13) + col] = acc[f][n][r];
                }
        return;
    }

    // triangle epilogue: cube; dtile: row-only with ri==cj skip;
    // strictly-upper: row + col (symmetry) sums.
    const bool dtile = ((bi >> 1) == bj);
    const int R0 = bi * 128, C0 = bj * 256;
    float rsum[4][4], csum[8];
#pragma unroll
    for (int n = 0; n < 8; ++n) csum[n] = 0.f;
#pragma unroll
    for (int f = 0; f < 4; ++f)
#pragma unroll
        for (int r = 0; r < 4; ++r) rsum[f][r] = 0.f;
#pragma unroll
    for (int f = 0; f < 4; ++f)
#pragma unroll
        for (int n = 0; n < 8; ++n)
#pragma unroll
            for (int r = 0; r < 4; ++r) {
                float s = acc[f][n][r];
                float c = s * s * s;
                int ri = R0 + wm * 64 + f * 16 + li4 * 4 + r;
                int cj = C0 + wn * 128 + n * 16 + l15;
                if (dtile && ri == cj) c = 0.f;
                rsum[f][r] += c;
                csum[n] += c;
            }
    // row side: reduce across the 16 col-lanes (l15)
#pragma unroll
    for (int o = 1; o < 16; o <<= 1)
#pragma unroll
        for (int f = 0; f < 4; ++f)
#pragma unroll
            for (int r = 0; r < 4; ++r)
                rsum[f][r] += __shfl_xor(rsum[f][r], o, 64);
    if (l15 == 0) {
#pragma unroll
        for (int f = 0; f < 4; ++f)
#pragma unroll
            for (int r = 0; r < 4; ++r)
                atomicAdd(&rc[R0 + wm * 64 + f * 16 + li4 * 4 + r], rsum[f][r]);
    }
    // col side (rows C0.. of S by symmetry; strictly-upper tiles only)
    if (!dtile) {
#pragma unroll
        for (int o = 16; o < 64; o <<= 1)
#pragma unroll
            for (int n = 0; n < 8; ++n) csum[n] += __shfl_xor(csum[n], o, 64);
        if (li4 == 0) {
#pragma unroll
            for (int n = 0; n < 8; ++n)
                atomicAdd(&rc[C0 + wn * 128 + n * 16 + l15], csum[n]);
        }
    }
}

// ---------------------------------------------------------------------------
// k_cubefin: per danger slot, correction = sum_c [(s0+s1+s2)^3 - s0^3]
// (skip c == drow; s0 bitwise-equals the triangle pass's hh value).
// ---------------------------------------------------------------------------
__global__ __launch_bounds__(256) void k_cubefin(const float* __restrict__ Sb,
                                                 const int* __restrict__ dlist,
                                                 float* __restrict__ rc) {
    const int slot = blockIdx.x;
    const int drow = dlist[slot];
    if (drow < 0) return;
    const int tid = threadIdx.x;
    const float* s0p = Sb + ((size_t)slot << 13);
    const float* s1p = Sb + ((size_t)(256 + slot) << 13);
    const float* s2p = Sb + ((size_t)(512 + slot) << 13);
    float sum = 0.f;
    for (int c = tid; c < VV; c += 256) {
        float s0 = s0p[c];
        float sf = s0 + s1p[c] + s2p[c];
        float d = sf * sf * sf - s0 * s0 * s0;
        if (c == drow) d = 0.f;
        sum += d;
    }
    __shared__ float red[256];
    red[tid] = sum;
    __syncthreads();
    for (int o = 128; o > 0; o >>= 1) {
        if (tid < o) red[tid] += red[tid + o];
        __syncthreads();
    }
    if (tid == 0) atomicAdd(&rc[drow], red[0]);
}

// ---------------------------------------------------------------------------
// k_final: out = collapse + 0.2 * sum_i rc_i / (mnum_i/8191 + 1e-6)
// ---------------------------------------------------------------------------
__global__ __launch_bounds__(1024) void k_final(const float* __restrict__ rc,
                                                const double* __restrict__ mnum,
                                                const double* __restrict__ dd,
                                                float* __restrict__ out) {
    int tid = threadIdx.x;
    double acc = 0.0, col = 0.0;
    for (int r = tid; r < VV; r += 1024) {
        double m = mnum[r] / 8191.0 + 1e-6;
        acc += (double)rc[r] / m;
        double dm = dd[r] - 1.0;
        col += dm * dm;
    }
    __shared__ double sa[1024], sc[1024];
    sa[tid] = acc;
    sc[tid] = col;
    __syncthreads();
    for (int o = 512; o > 0; o >>= 1) {
        if (tid < o) {
            sa[tid] += sa[tid + o];
            sc[tid] += sc[tid + o];
        }
        __syncthreads();
    }
    if (tid == 0) out[0] = (float)(sc[0] + 0.2 * sa[0]);
}

// ---------------------------------------------------------------------------
extern "C" void kernel_launch(void* const* d_in, const int* in_sizes, int n_in,
                              void* d_out, int out_size, void* d_ws, size_t ws_size,
                              hipStream_t stream) {
    const float* t = (const float*)d_in[0];
    float* out = (float*)d_out;

    char* ws = (char*)d_ws;
    float* Sb = (float*)ws;  // 3*256*8192*4B = 24 MB
    size_t off = (size_t)VV * DD * sizeof(float);  // keep 25.2 MB region
    ushort* xh = (ushort*)(ws + off); off += (size_t)VV * DD * sizeof(ushort);
    ushort* xl = (ushort*)(ws + off); off += (size_t)VV * DD * sizeof(ushort);
    double* g = (double*)(ws + off);  off += DD * sizeof(double);
    double* mnum = (double*)(ws + off); off += VV * sizeof(double);
    double* dd = (double*)(ws + off);  off += VV * sizeof(double);
    float* rc = (float*)(ws + off);    off += VV * sizeof(float);
    int* dlist = (int*)(ws + off);     off += NDMAX * sizeof(int);
    int* dcount = (int*)(ws + off);    off += sizeof(int) + 60;  // pad
    float* norms = (float*)(ws + off); off += VV * sizeof(float);
    double* gp = (double*)(ws + off);  off += (size_t)512 * DD * sizeof(double);

    k_normfused<<<512, 256, 0, stream>>>(t, norms, xh, xl, gp, rc, dlist, dcount);
    k_colsumB<<<24, 256, 0, stream>>>(gp, g);
    k_mean<<<VV / 4, 256, 0, stream>>>(t, norms, g, mnum, dd, dlist, dcount);
    k_cube<<<1248, 256, 0, stream>>>(xh, xl, dlist, Sb, rc);
    k_cubefin<<<NDMAX, 256, 0, stream>>>(Sb, dlist, rc);
    k_final<<<1, 1024, 0, stream>>>(rc, mnum, dd, out);
}